// Round 4
// baseline (217.198 us; speedup 1.0000x reference)
//
#include <hip/hip_runtime.h>
#include <cstdint>
#include <cstddef>

// Shapes fixed by the reference harness.
#define MM 2048
#define KK 4096
#define NN 4096
#define GG 32   // K / 128 groups
#define BM 128
#define BN 128
#define BK 64

typedef _Float16 half8_t __attribute__((ext_vector_type(8)));
typedef _Float16 half4_t __attribute__((ext_vector_type(4)));
typedef float f32x4 __attribute__((ext_vector_type(4)));

// Pass 1a: A fp32 -> fp16. Exact grid: MM*KK/4 threads, 4 elems each.
__global__ void cvt_a_kernel(const float* __restrict__ A, _Float16* __restrict__ Ah) {
  const int i = blockIdx.x * blockDim.x + threadIdx.x;
  const float4 v = ((const float4*)A)[i];
  half4_t h;
  h[0] = (_Float16)v.x; h[1] = (_Float16)v.y; h[2] = (_Float16)v.z; h[3] = (_Float16)v.w;
  *(half4_t*)(Ah + 4 * (size_t)i) = h;
}

// Pass 1b: W[n,k] = (q - z)*s -> fp16.  w = fma(q, s, -z*s).
__global__ void deq_w_kernel(const int* __restrict__ q, const float* __restrict__ scales,
                             const float* __restrict__ zeros, _Float16* __restrict__ Wh) {
  const int i = blockIdx.x * blockDim.x + threadIdx.x;
  const int e = i << 2;
  const int n = e >> 12;        // / KK
  const int k = e & (KK - 1);
  const int g = k >> 7;         // / 128
  const float sc = scales[(n << 5) + g];
  const float zp = zeros[(n << 5) + g];
  const float nzs = -zp * sc;
  const int4 qv = ((const int4*)q)[i];
  half4_t h;
  h[0] = (_Float16)fmaf((float)qv.x, sc, nzs);
  h[1] = (_Float16)fmaf((float)qv.y, sc, nzs);
  h[2] = (_Float16)fmaf((float)qv.z, sc, nzs);
  h[3] = (_Float16)fmaf((float)qv.w, sc, nzs);
  *(half4_t*)(Wh + (size_t)e) = h;
}

// BT-GEMM: out[m,n] = sum_k Ah[m,k] * Wh[n,k] + bias[n].
// 128x128 block tile, BK=64, 4 waves each computing 64x64 via 4x4 of 16x16x32 MFMA.
// LDS layout: row-major [128][64] fp16; bank behavior evened out by XOR swizzle
// of the 16B k-chunk with (row & 7).
// Staging: register path (global_load_dwordx4 -> ds_write_b128).
// FUSED=true variant stages through registers with inline convert/dequant
// (fallback when ws is too small).
template <bool FUSED>
__global__ __launch_bounds__(256, 2)
void gemm_kernel(const _Float16* __restrict__ Ah, const _Float16* __restrict__ Wh,
                 const float* __restrict__ Af, const int* __restrict__ qw,
                 const float* __restrict__ scales, const float* __restrict__ zeros,
                 const float* __restrict__ bias, float* __restrict__ out)
{
  __shared__ __align__(16) _Float16 sA[BM * BK];
  __shared__ __align__(16) _Float16 sB[BN * BK];

  const int tid = threadIdx.x;
  const int lane = tid & 63;
  const int wave = tid >> 6;
  const int wr = wave >> 1, wc = wave & 1;
  const int m0 = blockIdx.y * BM;
  const int n0 = blockIdx.x * BN;
  const int lr = lane & 15, quad = lane >> 4;

  f32x4 acc[4][4];
#pragma unroll
  for (int i = 0; i < 4; ++i)
#pragma unroll
    for (int j = 0; j < 4; ++j) acc[i][j] = (f32x4){0.f, 0.f, 0.f, 0.f};

  // register staging geometry: thread t covers rows p*32 + (t>>3), chunk t&7.
  const int srow = tid >> 3;   // 0..31
  const int scc = tid & 7;     // 16B chunk within 64-half row

  // fused staging geometry: 8 passes of 16 rows x 16 float4-cols.
  const int frow = tid >> 4;
  const int fc4 = tid & 15;

  for (int kt = 0; kt < KK / BK; ++kt) {
    const int k0 = kt * BK;
    if constexpr (!FUSED) {
      half8_t av[4], bv[4];
#pragma unroll
      for (int p = 0; p < 4; ++p) {
        const int row = p * 32 + srow;
        av[p] = *(const half8_t*)&Ah[(size_t)(m0 + row) * KK + k0 + scc * 8];
        bv[p] = *(const half8_t*)&Wh[(size_t)(n0 + row) * KK + k0 + scc * 8];
      }
#pragma unroll
      for (int p = 0; p < 4; ++p) {
        const int row = p * 32 + srow;
        const int dst = row * 64 + (scc ^ (row & 7)) * 8;
        *(half8_t*)&sA[dst] = av[p];
        *(half8_t*)&sB[dst] = bv[p];
      }
    } else {
      const int g = k0 >> 7;  // BK=64 tile lies in one 128-group
#pragma unroll
      for (int p = 0; p < 8; ++p) {
        const int row = p * 16 + frow;
        const int pc = (fc4 >> 1) ^ (row & 7);
        const int dst = row * 64 + pc * 8 + (fc4 & 1) * 4;
        const float4 avf = *(const float4*)&Af[(size_t)(m0 + row) * KK + k0 + fc4 * 4];
        half4_t ah;
        ah[0] = (_Float16)avf.x; ah[1] = (_Float16)avf.y;
        ah[2] = (_Float16)avf.z; ah[3] = (_Float16)avf.w;
        *(half4_t*)&sA[dst] = ah;
        const int n = n0 + row;
        const float sc = scales[(n << 5) + g];
        const float zp = zeros[(n << 5) + g];
        const float nzs = -zp * sc;
        const int4 qv = *(const int4*)&qw[(size_t)n * KK + k0 + fc4 * 4];
        half4_t bh;
        bh[0] = (_Float16)fmaf((float)qv.x, sc, nzs);
        bh[1] = (_Float16)fmaf((float)qv.y, sc, nzs);
        bh[2] = (_Float16)fmaf((float)qv.z, sc, nzs);
        bh[3] = (_Float16)fmaf((float)qv.w, sc, nzs);
        *(half4_t*)&sB[dst] = bh;
      }
    }
    __syncthreads();
#pragma unroll
    for (int ks = 0; ks < 2; ++ks) {
      half8_t a[4], b[4];
#pragma unroll
      for (int t = 0; t < 4; ++t) {
        // A-frag: A[m = lane&15][k = quad*8 + j]; rows differ by multiples of 8
        // outside lr, so row&7 == lr&7.
        const int rA = wr * 64 + t * 16 + lr;
        const int j = ks * 4 + quad;
        a[t] = *(const half8_t*)&sA[rA * 64 + ((j ^ (lr & 7)) * 8)];
        const int rB = wc * 64 + t * 16 + lr;
        b[t] = *(const half8_t*)&sB[rB * 64 + ((j ^ (lr & 7)) * 8)];
      }
#pragma unroll
      for (int mi = 0; mi < 4; ++mi)
#pragma unroll
        for (int ni = 0; ni < 4; ++ni)
          acc[mi][ni] = __builtin_amdgcn_mfma_f32_16x16x32_f16(a[mi], b[ni], acc[mi][ni], 0, 0, 0);
    }
    __syncthreads();
  }

  // Epilogue. C/D layout (verified, dtype-independent): col = lane&15,
  // row = quad*4 + reg.
#pragma unroll
  for (int ni = 0; ni < 4; ++ni) {
    const int n = n0 + wc * 64 + ni * 16 + lr;
    const float bv = bias[n];
#pragma unroll
    for (int mi = 0; mi < 4; ++mi) {
      const int mbase = m0 + wr * 64 + mi * 16 + quad * 4;
#pragma unroll
      for (int r = 0; r < 4; ++r)
        out[(size_t)(mbase + r) * NN + n] = acc[mi][ni][r] + bv;
    }
  }
}

extern "C" void kernel_launch(void* const* d_in, const int* in_sizes, int n_in,
                              void* d_out, int out_size, void* d_ws, size_t ws_size,
                              hipStream_t stream) {
  (void)in_sizes; (void)n_in; (void)out_size;
  const float* A      = (const float*)d_in[0];
  const int*   qw     = (const int*)d_in[1];
  const float* scales = (const float*)d_in[2];
  const float* zeros  = (const float*)d_in[3];
  const float* bias   = (const float*)d_in[4];
  float* out = (float*)d_out;

  const size_t needA = (size_t)MM * KK * sizeof(_Float16);  // 16 MB
  const size_t needW = (size_t)NN * KK * sizeof(_Float16);  // 32 MB

  dim3 grid(NN / BN, MM / BM);  // (32, 16)
  dim3 block(256);

  if (ws_size >= needA + needW) {
    _Float16* Ah = (_Float16*)d_ws;
    _Float16* Wh = (_Float16*)((char*)d_ws + needA);
    cvt_a_kernel<<<(MM * KK / 4) / 256, 256, 0, stream>>>(A, Ah);
    deq_w_kernel<<<(NN * KK / 4) / 256, 256, 0, stream>>>(qw, scales, zeros, Wh);
    gemm_kernel<false><<<grid, block, 0, stream>>>(Ah, Wh, A, qw, scales, zeros, bias, out);
  } else {
    gemm_kernel<true><<<grid, block, 0, stream>>>(nullptr, nullptr, A, qw, scales, zeros, bias, out);
  }
}

// Round 5
// 210.390 us; speedup vs baseline: 1.0324x; 1.0324x over previous
//
#include <hip/hip_runtime.h>
#include <cstdint>
#include <cstddef>

// Shapes fixed by the reference harness.
#define MM 2048
#define KK 4096
#define NN 4096
#define GG 32   // K / 128 groups
#define BM 128
#define BN 128
#define BK 64

typedef _Float16 half8_t __attribute__((ext_vector_type(8)));
typedef _Float16 half4_t __attribute__((ext_vector_type(4)));
typedef float f32x4 __attribute__((ext_vector_type(4)));

__device__ __forceinline__ void load_lds16(const void* gptr, void* lptr) {
  // 16B-per-lane direct global->LDS (emits global_load_lds_dwordx4).
  // LDS dest = wave-uniform base + lane*16 (NOT a per-lane scatter).
  __builtin_amdgcn_global_load_lds(
      (const __attribute__((address_space(1))) unsigned int*)gptr,
      (__attribute__((address_space(3))) unsigned int*)lptr, 16, 0, 0);
}

// Pass 1a: A fp32 -> fp16. Exact grid: MM*KK/4 threads, 4 elems each.
__global__ void cvt_a_kernel(const float* __restrict__ A, _Float16* __restrict__ Ah) {
  const int i = blockIdx.x * blockDim.x + threadIdx.x;
  const float4 v = ((const float4*)A)[i];
  half4_t h;
  h[0] = (_Float16)v.x; h[1] = (_Float16)v.y; h[2] = (_Float16)v.z; h[3] = (_Float16)v.w;
  *(half4_t*)(Ah + 4 * (size_t)i) = h;
}

// Pass 1b: W[n,k] = (q - z)*s -> fp16.  w = fma(q, s, -z*s).
__global__ void deq_w_kernel(const int* __restrict__ q, const float* __restrict__ scales,
                             const float* __restrict__ zeros, _Float16* __restrict__ Wh) {
  const int i = blockIdx.x * blockDim.x + threadIdx.x;
  const int e = i << 2;
  const int n = e >> 12;        // / KK
  const int k = e & (KK - 1);
  const int g = k >> 7;         // / 128
  const float sc = scales[(n << 5) + g];
  const float zp = zeros[(n << 5) + g];
  const float nzs = -zp * sc;
  const int4 qv = ((const int4*)q)[i];
  half4_t h;
  h[0] = (_Float16)fmaf((float)qv.x, sc, nzs);
  h[1] = (_Float16)fmaf((float)qv.y, sc, nzs);
  h[2] = (_Float16)fmaf((float)qv.z, sc, nzs);
  h[3] = (_Float16)fmaf((float)qv.w, sc, nzs);
  *(half4_t*)(Wh + (size_t)e) = h;
}

// BT-GEMM: out[m,n] = sum_k Ah[m,k] * Wh[n,k] + bias[n].
// 128x128 block tile, BK=64, 4 waves each computing 64x64 via 4x4 of 16x16x32 MFMA.
// LDS layout: row-major [128][64] fp16, NO padding (global_load_lds constraint);
// bank conflicts broken by XOR swizzle of the 16B k-chunk with (row & 7).
// R5 change vs R4: staging now uses global_load_lds width=16 (m93->m97 ladder
// step, 1.69x there). Geometry: 16 chunks of 1KB (8 rows x 64 halves); lane l
// covers row c*8 + l/8, physical 16B-chunk l%8, global chunk (l%8)^(row&7).
// FUSED=true variant stages through registers with inline convert/dequant
// (fallback when ws is too small).
template <bool FUSED>
__global__ __launch_bounds__(256, 2)
void gemm_kernel(const _Float16* __restrict__ Ah, const _Float16* __restrict__ Wh,
                 const float* __restrict__ Af, const int* __restrict__ qw,
                 const float* __restrict__ scales, const float* __restrict__ zeros,
                 const float* __restrict__ bias, float* __restrict__ out)
{
  __shared__ __align__(16) _Float16 sA[BM * BK];
  __shared__ __align__(16) _Float16 sB[BN * BK];

  const int tid = threadIdx.x;
  const int lane = tid & 63;
  const int wave = tid >> 6;
  const int wr = wave >> 1, wc = wave & 1;
  const int m0 = blockIdx.y * BM;
  const int n0 = blockIdx.x * BN;
  const int lr = lane & 15, quad = lane >> 4;

  f32x4 acc[4][4];
#pragma unroll
  for (int i = 0; i < 4; ++i)
#pragma unroll
    for (int j = 0; j < 4; ++j) acc[i][j] = (f32x4){0.f, 0.f, 0.f, 0.f};

  // global_load_lds staging geometry (see header comment).
  const int srow = lane >> 3;   // 0..7 within chunk
  const int scc = lane & 7;     // physical 16B chunk
  const int gchunk = scc ^ srow;  // (row&7)==srow&7 since c*8 is mult of 8

  // fused staging geometry: 8 passes of 16 rows x 16 float4-cols.
  const int frow = tid >> 4;
  const int fc4 = tid & 15;

  for (int kt = 0; kt < KK / BK; ++kt) {
    const int k0 = kt * BK;
    if constexpr (!FUSED) {
#pragma unroll
      for (int i = 0; i < 4; ++i) {
        const int c = i * 4 + wave;     // wave-uniform chunk id 0..15
        const int row = c * 8 + srow;
        load_lds16(Ah + (size_t)(m0 + row) * KK + k0 + gchunk * 8, (void*)&sA[c * 512]);
        load_lds16(Wh + (size_t)(n0 + row) * KK + k0 + gchunk * 8, (void*)&sB[c * 512]);
      }
    } else {
      const int g = k0 >> 7;  // BK=64 tile lies in one 128-group
#pragma unroll
      for (int p = 0; p < 8; ++p) {
        const int row = p * 16 + frow;
        const int pc = (fc4 >> 1) ^ (row & 7);
        const int dst = row * 64 + pc * 8 + (fc4 & 1) * 4;
        const float4 avf = *(const float4*)&Af[(size_t)(m0 + row) * KK + k0 + fc4 * 4];
        half4_t ah;
        ah[0] = (_Float16)avf.x; ah[1] = (_Float16)avf.y;
        ah[2] = (_Float16)avf.z; ah[3] = (_Float16)avf.w;
        *(half4_t*)&sA[dst] = ah;
        const int n = n0 + row;
        const float sc = scales[(n << 5) + g];
        const float zp = zeros[(n << 5) + g];
        const float nzs = -zp * sc;
        const int4 qv = *(const int4*)&qw[(size_t)n * KK + k0 + fc4 * 4];
        half4_t bh;
        bh[0] = (_Float16)fmaf((float)qv.x, sc, nzs);
        bh[1] = (_Float16)fmaf((float)qv.y, sc, nzs);
        bh[2] = (_Float16)fmaf((float)qv.z, sc, nzs);
        bh[3] = (_Float16)fmaf((float)qv.w, sc, nzs);
        *(half4_t*)&sB[dst] = bh;
      }
    }
    __syncthreads();
#pragma unroll
    for (int ks = 0; ks < 2; ++ks) {
      half8_t a[4], b[4];
#pragma unroll
      for (int t = 0; t < 4; ++t) {
        // A-frag: A[m = lane&15][k = quad*8 + j]; rows differ by multiples of 8
        // outside lr, so row&7 == lr&7.
        const int rA = wr * 64 + t * 16 + lr;
        const int j = ks * 4 + quad;
        a[t] = *(const half8_t*)&sA[rA * 64 + ((j ^ (lr & 7)) * 8)];
        const int rB = wc * 64 + t * 16 + lr;
        b[t] = *(const half8_t*)&sB[rB * 64 + ((j ^ (lr & 7)) * 8)];
      }
#pragma unroll
      for (int mi = 0; mi < 4; ++mi)
#pragma unroll
        for (int ni = 0; ni < 4; ++ni)
          acc[mi][ni] = __builtin_amdgcn_mfma_f32_16x16x32_f16(a[mi], b[ni], acc[mi][ni], 0, 0, 0);
    }
    __syncthreads();
  }

  // Epilogue. C/D layout (verified, dtype-independent): col = lane&15,
  // row = quad*4 + reg.
#pragma unroll
  for (int ni = 0; ni < 4; ++ni) {
    const int n = n0 + wc * 64 + ni * 16 + lr;
    const float bv = bias[n];
#pragma unroll
    for (int mi = 0; mi < 4; ++mi) {
      const int mbase = m0 + wr * 64 + mi * 16 + quad * 4;
#pragma unroll
      for (int r = 0; r < 4; ++r)
        out[(size_t)(mbase + r) * NN + n] = acc[mi][ni][r] + bv;
    }
  }
}

extern "C" void kernel_launch(void* const* d_in, const int* in_sizes, int n_in,
                              void* d_out, int out_size, void* d_ws, size_t ws_size,
                              hipStream_t stream) {
  (void)in_sizes; (void)n_in; (void)out_size;
  const float* A      = (const float*)d_in[0];
  const int*   qw     = (const int*)d_in[1];
  const float* scales = (const float*)d_in[2];
  const float* zeros  = (const float*)d_in[3];
  const float* bias   = (const float*)d_in[4];
  float* out = (float*)d_out;

  const size_t needA = (size_t)MM * KK * sizeof(_Float16);  // 16 MB
  const size_t needW = (size_t)NN * KK * sizeof(_Float16);  // 32 MB

  dim3 grid(NN / BN, MM / BM);  // (32, 16)
  dim3 block(256);

  if (ws_size >= needA + needW) {
    _Float16* Ah = (_Float16*)d_ws;
    _Float16* Wh = (_Float16*)((char*)d_ws + needA);
    cvt_a_kernel<<<(MM * KK / 4) / 256, 256, 0, stream>>>(A, Ah);
    deq_w_kernel<<<(NN * KK / 4) / 256, 256, 0, stream>>>(qw, scales, zeros, Wh);
    gemm_kernel<false><<<grid, block, 0, stream>>>(Ah, Wh, A, qw, scales, zeros, bias, out);
  } else {
    gemm_kernel<true><<<grid, block, 0, stream>>>(nullptr, nullptr, A, qw, scales, zeros, bias, out);
  }
}

// Round 6
// 204.491 us; speedup vs baseline: 1.0621x; 1.0288x over previous
//
#include <hip/hip_runtime.h>
#include <cstdint>
#include <cstddef>

// Shapes fixed by the reference harness.
#define MM 2048
#define KK 4096
#define NN 4096
#define GG 32   // K / 128 groups
#define BM 128
#define BN 128
#define BK 64

typedef _Float16 half8_t __attribute__((ext_vector_type(8)));
typedef _Float16 half4_t __attribute__((ext_vector_type(4)));
typedef float f32x4 __attribute__((ext_vector_type(4)));

__device__ __forceinline__ void load_lds16(const void* gptr, void* lptr) {
  // 16B-per-lane direct global->LDS (emits global_load_lds_dwordx4).
  // LDS dest = wave-uniform base + lane*16 (NOT a per-lane scatter).
  __builtin_amdgcn_global_load_lds(
      (const __attribute__((address_space(1))) unsigned int*)gptr,
      (__attribute__((address_space(3))) unsigned int*)lptr, 16, 0, 0);
}

// Merged prep: first MM*KK/4 threads convert A fp32->fp16; the rest dequant
// qweight -> fp16 via w = fma(q, s, -z*s). Block-uniform branch (boundary
// divisible by block size).
#define ACNT (MM * KK / 4)   // 2M float4-threads for A
__global__ void prep_kernel(const float* __restrict__ A, const int* __restrict__ q,
                            const float* __restrict__ scales, const float* __restrict__ zeros,
                            _Float16* __restrict__ Ah, _Float16* __restrict__ Wh) {
  const int i = blockIdx.x * blockDim.x + threadIdx.x;
  if (i < ACNT) {
    const float4 v = ((const float4*)A)[i];
    half4_t h;
    h[0] = (_Float16)v.x; h[1] = (_Float16)v.y; h[2] = (_Float16)v.z; h[3] = (_Float16)v.w;
    *(half4_t*)(Ah + 4 * (size_t)i) = h;
  } else {
    const int j = i - ACNT;
    const int e = j << 2;
    const int n = e >> 12;        // / KK
    const int k = e & (KK - 1);
    const int g = k >> 7;         // / 128
    const float sc = scales[(n << 5) + g];
    const float zp = zeros[(n << 5) + g];
    const float nzs = -zp * sc;
    const int4 qv = ((const int4*)q)[j];
    half4_t h;
    h[0] = (_Float16)fmaf((float)qv.x, sc, nzs);
    h[1] = (_Float16)fmaf((float)qv.y, sc, nzs);
    h[2] = (_Float16)fmaf((float)qv.z, sc, nzs);
    h[3] = (_Float16)fmaf((float)qv.w, sc, nzs);
    *(half4_t*)(Wh + (size_t)e) = h;
  }
}

// BT-GEMM: out[m,n] = sum_k Ah[m,k] * Wh[n,k] + bias[n].
// 128x128 block tile, BK=64, 4 waves each computing 64x64 via 4x4 of 16x16x32 MFMA.
// LDS layout: row-major [128][64] fp16, NO padding (global_load_lds constraint);
// bank conflicts broken by XOR swizzle of the 16B k-chunk with (row & 7).
// Staging: global_load_lds width=16 (m97 ladder step).
// R6 change: XCD-aware block swizzle. Workgroup dispatch round-robins XCDs by
// block index; remap so XCD (bid&7) owns n-tile columns [xcd*4, xcd*4+4),
// slots sweep the 4 n-tiles per m-row -> per-k-step XCD working set ~320KB
// fits the 4MB per-XCD L2 -> staging loads hit L2 (~200cyc) instead of
// L3 (~450cyc), shortening the pre-barrier vmcnt(0) drain.
// FUSED=true variant stages through registers with inline convert/dequant
// (fallback when ws is too small).
template <bool FUSED>
__global__ __launch_bounds__(256, 2)
void gemm_kernel(const _Float16* __restrict__ Ah, const _Float16* __restrict__ Wh,
                 const float* __restrict__ Af, const int* __restrict__ qw,
                 const float* __restrict__ scales, const float* __restrict__ zeros,
                 const float* __restrict__ bias, float* __restrict__ out)
{
  __shared__ __align__(16) _Float16 sA[BM * BK];
  __shared__ __align__(16) _Float16 sB[BN * BK];

  const int tid = threadIdx.x;
  const int lane = tid & 63;
  const int wave = tid >> 6;
  const int wr = wave >> 1, wc = wave & 1;

  // XCD-aware swizzle (1D grid of 512 blocks; 8 XCDs round-robin by bid).
  const int bid = blockIdx.x;
  const int xcd = bid & 7;
  const int slot = bid >> 3;           // 0..63 within XCD
  const int mt = slot >> 2;            // 0..15
  const int nt = xcd * 4 + (slot & 3); // 0..31
  const int m0 = mt * BM;
  const int n0 = nt * BN;

  const int lr = lane & 15, quad = lane >> 4;

  f32x4 acc[4][4];
#pragma unroll
  for (int i = 0; i < 4; ++i)
#pragma unroll
    for (int j = 0; j < 4; ++j) acc[i][j] = (f32x4){0.f, 0.f, 0.f, 0.f};

  // global_load_lds staging geometry: 16 chunks of 1KB (8 rows x 64 halves);
  // lane l covers row c*8 + l/8, physical 16B-chunk l%8, global chunk
  // (l%8)^(row&7).
  const int srow = lane >> 3;   // 0..7 within chunk
  const int scc = lane & 7;     // physical 16B chunk
  const int gchunk = scc ^ srow;

  // fused staging geometry: 8 passes of 16 rows x 16 float4-cols.
  const int frow = tid >> 4;
  const int fc4 = tid & 15;

  for (int kt = 0; kt < KK / BK; ++kt) {
    const int k0 = kt * BK;
    if constexpr (!FUSED) {
#pragma unroll
      for (int i = 0; i < 4; ++i) {
        const int c = i * 4 + wave;     // wave-uniform chunk id 0..15
        const int row = c * 8 + srow;
        load_lds16(Ah + (size_t)(m0 + row) * KK + k0 + gchunk * 8, (void*)&sA[c * 512]);
        load_lds16(Wh + (size_t)(n0 + row) * KK + k0 + gchunk * 8, (void*)&sB[c * 512]);
      }
    } else {
      const int g = k0 >> 7;  // BK=64 tile lies in one 128-group
#pragma unroll
      for (int p = 0; p < 8; ++p) {
        const int row = p * 16 + frow;
        const int pc = (fc4 >> 1) ^ (row & 7);
        const int dst = row * 64 + pc * 8 + (fc4 & 1) * 4;
        const float4 avf = *(const float4*)&Af[(size_t)(m0 + row) * KK + k0 + fc4 * 4];
        half4_t ah;
        ah[0] = (_Float16)avf.x; ah[1] = (_Float16)avf.y;
        ah[2] = (_Float16)avf.z; ah[3] = (_Float16)avf.w;
        *(half4_t*)&sA[dst] = ah;
        const int n = n0 + row;
        const float sc = scales[(n << 5) + g];
        const float zp = zeros[(n << 5) + g];
        const float nzs = -zp * sc;
        const int4 qv = *(const int4*)&qw[(size_t)n * KK + k0 + fc4 * 4];
        half4_t bh;
        bh[0] = (_Float16)fmaf((float)qv.x, sc, nzs);
        bh[1] = (_Float16)fmaf((float)qv.y, sc, nzs);
        bh[2] = (_Float16)fmaf((float)qv.z, sc, nzs);
        bh[3] = (_Float16)fmaf((float)qv.w, sc, nzs);
        *(half4_t*)&sB[dst] = bh;
      }
    }
    __syncthreads();
#pragma unroll
    for (int ks = 0; ks < 2; ++ks) {
      half8_t a[4], b[4];
#pragma unroll
      for (int t = 0; t < 4; ++t) {
        // A-frag: A[m = lane&15][k = quad*8 + j]; rows differ by multiples of 8
        // outside lr, so row&7 == lr&7.
        const int rA = wr * 64 + t * 16 + lr;
        const int j = ks * 4 + quad;
        a[t] = *(const half8_t*)&sA[rA * 64 + ((j ^ (lr & 7)) * 8)];
        const int rB = wc * 64 + t * 16 + lr;
        b[t] = *(const half8_t*)&sB[rB * 64 + ((j ^ (lr & 7)) * 8)];
      }
#pragma unroll
      for (int mi = 0; mi < 4; ++mi)
#pragma unroll
        for (int ni = 0; ni < 4; ++ni)
          acc[mi][ni] = __builtin_amdgcn_mfma_f32_16x16x32_f16(a[mi], b[ni], acc[mi][ni], 0, 0, 0);
    }
    __syncthreads();
  }

  // Epilogue. C/D layout (verified, dtype-independent): col = lane&15,
  // row = quad*4 + reg.
#pragma unroll
  for (int ni = 0; ni < 4; ++ni) {
    const int n = n0 + wc * 64 + ni * 16 + lr;
    const float bv = bias[n];
#pragma unroll
    for (int mi = 0; mi < 4; ++mi) {
      const int mbase = m0 + wr * 64 + mi * 16 + quad * 4;
#pragma unroll
      for (int r = 0; r < 4; ++r)
        out[(size_t)(mbase + r) * NN + n] = acc[mi][ni][r] + bv;
    }
  }
}

extern "C" void kernel_launch(void* const* d_in, const int* in_sizes, int n_in,
                              void* d_out, int out_size, void* d_ws, size_t ws_size,
                              hipStream_t stream) {
  (void)in_sizes; (void)n_in; (void)out_size;
  const float* A      = (const float*)d_in[0];
  const int*   qw     = (const int*)d_in[1];
  const float* scales = (const float*)d_in[2];
  const float* zeros  = (const float*)d_in[3];
  const float* bias   = (const float*)d_in[4];
  float* out = (float*)d_out;

  const size_t needA = (size_t)MM * KK * sizeof(_Float16);  // 16 MB
  const size_t needW = (size_t)NN * KK * sizeof(_Float16);  // 32 MB

  dim3 grid(NN / BN * MM / BM);  // 512, 1D for XCD swizzle
  dim3 block(256);

  if (ws_size >= needA + needW) {
    _Float16* Ah = (_Float16*)d_ws;
    _Float16* Wh = (_Float16*)((char*)d_ws + needA);
    prep_kernel<<<((MM + NN) * KK / 4) / 256, 256, 0, stream>>>(A, qw, scales, zeros, Ah, Wh);
    gemm_kernel<false><<<grid, block, 0, stream>>>(Ah, Wh, A, qw, scales, zeros, bias, out);
  } else {
    gemm_kernel<true><<<grid, block, 0, stream>>>(nullptr, nullptr, A, qw, scales, zeros, bias, out);
  }
}